// Round 3
// baseline (800.166 us; speedup 1.0000x reference)
//
#include <hip/hip_runtime.h>
#include <hip/hip_cooperative_groups.h>
#include <hip/hip_bf16.h>
#include <math.h>

namespace cg = cooperative_groups;

typedef __attribute__((ext_vector_type(8))) short short8;   // 8 bf16 (4 VGPRs)
typedef __attribute__((ext_vector_type(4))) float f32x4;
typedef __attribute__((ext_vector_type(4))) unsigned short us4;
typedef __attribute__((ext_vector_type(8))) unsigned short us8;

__device__ __forceinline__ float us2f(unsigned short u) {
    return __uint_as_float(((unsigned)u) << 16);
}
__device__ __forceinline__ unsigned short f2us_rtn(float f) {
    return (unsigned short)__bfloat16_as_ushort(__float2bfloat16(f));  // RTN
}

#define LP 72

// ================= LDS-free GEMM tile (mega path) ============================
// 64x128 tile, 4 waves (2x2). Fragments read directly from global; k-index
// math identical to the verified LDS layout, so MFMA inputs are bit-identical.
// EPI=0: GAT layer (write C bf16 + fused as/ad dots + atomics)
// EPI=1: head1    (write relu(acc+bias) as fp32 to Cf)
template <int EPI>
__device__ __forceinline__ void gemm_nolds(const unsigned short* __restrict__ A,
                                           const unsigned short* __restrict__ Bt,
                                           const float* __restrict__ avs,
                                           const float* __restrict__ avd,
                                           float* __restrict__ as_,
                                           float* __restrict__ ad_,
                                           unsigned short* __restrict__ C,
                                           float* __restrict__ Cf,
                                           int M, int Nn, int K, int row0, int col0) {
    const int tid = threadIdx.x;
    const int wave = tid >> 6, lane = tid & 63;
    const int m16 = lane & 15, quad = lane >> 4;
    const int wr = (wave >> 1) * 32, wc = (wave & 1) * 64;
    const unsigned short* Ap[2];
#pragma unroll
    for (int mi = 0; mi < 2; mi++) {
        int r = row0 + wr + mi * 16 + m16;
        if (r >= M) r = M - 1;
        Ap[mi] = A + (size_t)r * K + quad * 8;
    }
    const unsigned short* Bp[4];
#pragma unroll
    for (int ni = 0; ni < 4; ni++)
        Bp[ni] = Bt + (size_t)(col0 + wc + ni * 16 + m16) * K + quad * 8;

    f32x4 acc[2][4] = {};
    short8 ca0 = *(const short8*)Ap[0];
    short8 ca1 = *(const short8*)Ap[1];
    short8 cb0 = *(const short8*)Bp[0];
    short8 cb1 = *(const short8*)Bp[1];
    short8 cb2 = *(const short8*)Bp[2];
    short8 cb3 = *(const short8*)Bp[3];
    for (int k0 = 32;; k0 += 32) {
        const bool more = k0 < K;
        short8 na0, na1, nb0, nb1, nb2, nb3;
        if (more) {                           // next fragments in flight under MFMA
            na0 = *(const short8*)(Ap[0] + k0);
            na1 = *(const short8*)(Ap[1] + k0);
            nb0 = *(const short8*)(Bp[0] + k0);
            nb1 = *(const short8*)(Bp[1] + k0);
            nb2 = *(const short8*)(Bp[2] + k0);
            nb3 = *(const short8*)(Bp[3] + k0);
        }
        acc[0][0] = __builtin_amdgcn_mfma_f32_16x16x32_bf16(ca0, cb0, acc[0][0], 0, 0, 0);
        acc[1][0] = __builtin_amdgcn_mfma_f32_16x16x32_bf16(ca1, cb0, acc[1][0], 0, 0, 0);
        acc[0][1] = __builtin_amdgcn_mfma_f32_16x16x32_bf16(ca0, cb1, acc[0][1], 0, 0, 0);
        acc[1][1] = __builtin_amdgcn_mfma_f32_16x16x32_bf16(ca1, cb1, acc[1][1], 0, 0, 0);
        acc[0][2] = __builtin_amdgcn_mfma_f32_16x16x32_bf16(ca0, cb2, acc[0][2], 0, 0, 0);
        acc[1][2] = __builtin_amdgcn_mfma_f32_16x16x32_bf16(ca1, cb2, acc[1][2], 0, 0, 0);
        acc[0][3] = __builtin_amdgcn_mfma_f32_16x16x32_bf16(ca0, cb3, acc[0][3], 0, 0, 0);
        acc[1][3] = __builtin_amdgcn_mfma_f32_16x16x32_bf16(ca1, cb3, acc[1][3], 0, 0, 0);
        if (!more) break;
        ca0 = na0; ca1 = na1;
        cb0 = nb0; cb1 = nb1; cb2 = nb2; cb3 = nb3;
    }
    // epilogue: C/D layout col=lane&15, row=quad*4+r [m89-verified]
    if constexpr (EPI == 0) {
        float ps[2][4] = {}, pd[2][4] = {};
#pragma unroll
        for (int mi = 0; mi < 2; mi++) {
            const int orow_base = row0 + wr + mi * 16 + quad * 4;
#pragma unroll
            for (int ni = 0; ni < 4; ni++) {
                const int ocol = col0 + wc + ni * 16 + m16;
                const float asv = avs[ocol], adv = avd[ocol];
#pragma unroll
                for (int r = 0; r < 4; r++) {
                    const int orow = orow_base + r;
                    if (orow < M) {
                        const float v = acc[mi][ni][r];
                        C[(size_t)orow * Nn + ocol] = f2us_rtn(v);
                        ps[mi][r] = fmaf(v, asv, ps[mi][r]);
                        pd[mi][r] = fmaf(v, adv, pd[mi][r]);
                    }
                }
            }
        }
#pragma unroll
        for (int mi = 0; mi < 2; mi++)
#pragma unroll
            for (int r = 0; r < 4; r++)
#pragma unroll
                for (int off = 1; off < 16; off <<= 1) {
                    ps[mi][r] += __shfl_xor(ps[mi][r], off);
                    pd[mi][r] += __shfl_xor(pd[mi][r], off);
                }
        if (m16 == 0) {
#pragma unroll
            for (int mi = 0; mi < 2; mi++) {
                const int orow_base = row0 + wr + mi * 16 + quad * 4;
#pragma unroll
                for (int r = 0; r < 4; r++) {
                    const int orow = orow_base + r;
                    if (orow < M) {
                        atomicAdd(&as_[orow], ps[mi][r]);
                        atomicAdd(&ad_[orow], pd[mi][r]);
                    }
                }
            }
        }
    } else {
#pragma unroll
        for (int mi = 0; mi < 2; mi++) {
            const int orow_base = row0 + wr + mi * 16 + quad * 4;
#pragma unroll
            for (int ni = 0; ni < 4; ni++) {
                const int ocol = col0 + wc + ni * 16 + m16;
                const float b1v = avs[ocol];
#pragma unroll
                for (int r = 0; r < 4; r++) {
                    const int orow = orow_base + r;
                    if (orow < M)
                        Cf[(size_t)orow * Nn + ocol] = fmaxf(acc[mi][ni][r] + b1v, 0.f);
                }
            }
        }
    }
}

// ================= LDS-staged bodies (proven fallback path) ==================
__device__ __forceinline__ void gemm_tile(const unsigned short* __restrict__ A,
                                          const unsigned short* __restrict__ Bt,
                                          const float* __restrict__ avs,
                                          const float* __restrict__ avd,
                                          float* __restrict__ as_,
                                          float* __restrict__ ad_,
                                          unsigned short* __restrict__ C,
                                          int M, int Nn, int K, int row0, int col0,
                                          unsigned short* sA, unsigned short* sB) {
    const int tid = threadIdx.x;
    const int wave = tid >> 6, lane = tid & 63;
    const int m16 = lane & 15, quad = lane >> 4;
    const int wr = (wave >> 1) * 32, wc = (wave & 1) * 64;
    const int ar = tid >> 2, akc = (tid & 3) * 8;
    const int bkc = (tid & 7) * 8, bcb = tid >> 3;
    const int gr = (row0 + ar) < M ? (row0 + ar) : (M - 1);
    const unsigned short* Arow = A + (size_t)gr * K + akc;
    const unsigned short* Bcol = Bt + (size_t)(col0 + bcb) * K + bkc;

    short8 rA0, rA1, rb0, rb1, rb2, rb3;
    auto LOADT = [&](int k0) {
        rA0 = *(const short8*)(Arow + k0);
        rA1 = *(const short8*)(Arow + k0 + 32);
        rb0 = *(const short8*)(Bcol + k0);
        rb1 = *(const short8*)(Bcol + (size_t)32 * K + k0);
        rb2 = *(const short8*)(Bcol + (size_t)64 * K + k0);
        rb3 = *(const short8*)(Bcol + (size_t)96 * K + k0);
    };
    auto STORET = [&]() {
        *(short8*)&sA[ar * LP + akc]      = rA0;
        *(short8*)&sA[ar * LP + akc + 32] = rA1;
        *(short8*)&sB[bcb * LP + bkc]        = rb0;
        *(short8*)&sB[(bcb + 32) * LP + bkc] = rb1;
        *(short8*)&sB[(bcb + 64) * LP + bkc] = rb2;
        *(short8*)&sB[(bcb + 96) * LP + bkc] = rb3;
    };

    f32x4 acc[2][4] = {};
    LOADT(0);
    STORET();
    __syncthreads();
    for (int k0 = 0; k0 < K; k0 += 64) {
        const bool more = (k0 + 64) < K;
        if (more) LOADT(k0 + 64);
#pragma unroll
        for (int ks = 0; ks < 2; ks++) {
            short8 ah[2];
#pragma unroll
            for (int mi = 0; mi < 2; mi++)
                ah[mi] = *(const short8*)&sA[(wr + mi * 16 + m16) * LP + ks * 32 + quad * 8];
#pragma unroll
            for (int ni = 0; ni < 4; ni++) {
                const short8 bv = *(const short8*)&sB[(wc + ni * 16 + m16) * LP + ks * 32 + quad * 8];
#pragma unroll
                for (int mi = 0; mi < 2; mi++)
                    acc[mi][ni] = __builtin_amdgcn_mfma_f32_16x16x32_bf16(ah[mi], bv, acc[mi][ni], 0, 0, 0);
            }
        }
        __syncthreads();
        if (more) { STORET(); __syncthreads(); }
    }
    float ps[2][4] = {}, pd[2][4] = {};
#pragma unroll
    for (int mi = 0; mi < 2; mi++) {
        const int orow_base = row0 + wr + mi * 16 + quad * 4;
#pragma unroll
        for (int ni = 0; ni < 4; ni++) {
            const int ocol = col0 + wc + ni * 16 + m16;
            const float asv = avs[ocol], adv = avd[ocol];
#pragma unroll
            for (int r = 0; r < 4; r++) {
                const int orow = orow_base + r;
                if (orow < M) {
                    const float v = acc[mi][ni][r];
                    C[(size_t)orow * Nn + ocol] = f2us_rtn(v);
                    ps[mi][r] = fmaf(v, asv, ps[mi][r]);
                    pd[mi][r] = fmaf(v, adv, pd[mi][r]);
                }
            }
        }
    }
#pragma unroll
    for (int mi = 0; mi < 2; mi++)
#pragma unroll
        for (int r = 0; r < 4; r++)
#pragma unroll
            for (int off = 1; off < 16; off <<= 1) {
                ps[mi][r] += __shfl_xor(ps[mi][r], off);
                pd[mi][r] += __shfl_xor(pd[mi][r], off);
            }
    if (m16 == 0) {
#pragma unroll
        for (int mi = 0; mi < 2; mi++) {
            const int orow_base = row0 + wr + mi * 16 + quad * 4;
#pragma unroll
            for (int r = 0; r < 4; r++) {
                const int orow = orow_base + r;
                if (orow < M) {
                    atomicAdd(&as_[orow], ps[mi][r]);
                    atomicAdd(&ad_[orow], pd[mi][r]);
                }
            }
        }
    }
}

__device__ __forceinline__ void head_tile(const unsigned short* __restrict__ A,
                                          const unsigned short* __restrict__ Bt,
                                          const float* __restrict__ bias1,
                                          const float* __restrict__ W2,
                                          const float* __restrict__ bias2,
                                          float* __restrict__ out,
                                          int M, int K, int Aout, int row0,
                                          unsigned short* sA, unsigned short* sB,
                                          float* pLDS) {
    const int tid = threadIdx.x;
    const int wave = tid >> 6, lane = tid & 63;
    const int m16 = lane & 15, quad = lane >> 4;
    const int wr = (wave >> 1) * 32, wc = (wave & 1) * 128;
    const int ar = tid >> 2, akc = (tid & 3) * 8;
    const int bkc = (tid & 7) * 8, bcb = tid >> 3;
    const int gr = (row0 + ar) < M ? (row0 + ar) : (M - 1);
    const unsigned short* Arow = A + (size_t)gr * K + akc;
    const unsigned short* Bcol = Bt + (size_t)bcb * K + bkc;

    short8 rA0, rA1, rb[8];
    auto LOADT = [&](int k0) {
        rA0 = *(const short8*)(Arow + k0);
        rA1 = *(const short8*)(Arow + k0 + 32);
#pragma unroll
        for (int q = 0; q < 8; q++)
            rb[q] = *(const short8*)(Bcol + (size_t)(32 * q) * K + k0);
    };
    auto STORET = [&]() {
        *(short8*)&sA[ar * LP + akc]      = rA0;
        *(short8*)&sA[ar * LP + akc + 32] = rA1;
#pragma unroll
        for (int q = 0; q < 8; q++)
            *(short8*)&sB[(bcb + 32 * q) * LP + bkc] = rb[q];
    };

    f32x4 acc[2][8] = {};
    LOADT(0);
    STORET();
    __syncthreads();
    for (int k0 = 0; k0 < K; k0 += 64) {
        const bool more = (k0 + 64) < K;
        if (more) LOADT(k0 + 64);
#pragma unroll
        for (int ks = 0; ks < 2; ks++) {
            short8 ah[2];
#pragma unroll
            for (int mi = 0; mi < 2; mi++)
                ah[mi] = *(const short8*)&sA[(wr + mi * 16 + m16) * LP + ks * 32 + quad * 8];
#pragma unroll
            for (int ni = 0; ni < 8; ni++) {
                const short8 bv = *(const short8*)&sB[(wc + ni * 16 + m16) * LP + ks * 32 + quad * 8];
#pragma unroll
                for (int mi = 0; mi < 2; mi++)
                    acc[mi][ni] = __builtin_amdgcn_mfma_f32_16x16x32_bf16(ah[mi], bv, acc[mi][ni], 0, 0, 0);
            }
        }
        __syncthreads();
        if (more) { STORET(); __syncthreads(); }
    }
    float p[2][4][8] = {};
#pragma unroll
    for (int ni = 0; ni < 8; ni++) {
        const int ocol = wc + ni * 16 + m16;
        const float b1v = bias1[ocol];
        float w2[8];
#pragma unroll
        for (int a = 0; a < 8; a++) w2[a] = W2[ocol * 8 + a];
#pragma unroll
        for (int mi = 0; mi < 2; mi++)
#pragma unroll
            for (int r = 0; r < 4; r++) {
                const float v = fmaxf(acc[mi][ni][r] + b1v, 0.f);
#pragma unroll
                for (int a = 0; a < 8; a++) p[mi][r][a] = fmaf(v, w2[a], p[mi][r][a]);
            }
    }
#pragma unroll
    for (int off = 1; off < 16; off <<= 1)
#pragma unroll
        for (int mi = 0; mi < 2; mi++)
#pragma unroll
            for (int r = 0; r < 4; r++)
#pragma unroll
                for (int a = 0; a < 8; a++) p[mi][r][a] += __shfl_xor(p[mi][r][a], off);
    if (m16 == 0) {
        const int half = wc >> 7;
#pragma unroll
        for (int mi = 0; mi < 2; mi++) {
            const int lrow = wr + mi * 16 + quad * 4;
#pragma unroll
            for (int r = 0; r < 4; r++)
#pragma unroll
                for (int a = 0; a < 8; a++)
                    pLDS[(half * 64 + lrow + r) * 8 + a] = p[mi][r][a];
        }
    }
    __syncthreads();
#pragma unroll
    for (int u = 0; u < 2; u++) {
        const int idx = tid * 2 + u;
        const int lrow = idx >> 3, a = idx & 7;
        const int orow = row0 + lrow;
        if (orow < M && a < Aout)
            out[(size_t)orow * Aout + a] =
                tanhf(pLDS[(0 * 64 + lrow) * 8 + a] + pLDS[(1 * 64 + lrow) * 8 + a] + bias2[a]);
    }
}

// ---- wave/node softmax+aggregate (grid-stride, no early return) -------------
__device__ __forceinline__ void agg_phase(const unsigned short* __restrict__ hb,
                                          const int* __restrict__ offs,
                                          const int* __restrict__ esrc,
                                          const float* __restrict__ as_,
                                          const float* __restrict__ ad_,
                                          const float* __restrict__ bias,
                                          unsigned short* __restrict__ xout,
                                          int N, int nwaves) {
    const int w0 = blockIdx.x * 4 + (threadIdx.x >> 6);
    const int lane = threadIdx.x & 63;
    const int half = lane >> 5;
    const int f0 = (lane & 31) * 8;
    for (int n0 = w0; n0 < N; n0 += nwaves) {
        const int n = __builtin_amdgcn_readfirstlane(n0);
        const int b = offs[n], e2 = offs[n + 1];
        const float adn = ad_[n];
        float a[8] = {};
        float wsum = 0.f;
        for (int c0 = b; c0 < e2; c0 += 16) {
            int s = 0;
            float w = 0.f;
            if (lane < 16) {
                const int j = c0 + lane;
                const int jj = j < e2 ? j : e2 - 1;   // self-loop guarantees >= 1 edge
                s = esrc[jj];
                if (j < e2) {
                    float v = as_[s] + adn;
                    v = v > 0.f ? v : 0.2f * v;
                    w = __expf(v);
                    wsum += w;
                }
            }
            us8 pv[8];
            float wb[8];
#pragma unroll
            for (int u = 0; u < 8; u++) {
                const int el = 2 * u + half;
                const int su = __shfl(s, el);
                wb[u] = __shfl(w, el);
                pv[u] = *(const us8*)(hb + (unsigned)((su << 8) + f0));
            }
#pragma unroll
            for (int u = 0; u < 8; u++)
#pragma unroll
                for (int j2 = 0; j2 < 8; j2++)
                    a[j2] = fmaf(wb[u], us2f(pv[u][j2]), a[j2]);
        }
#pragma unroll
        for (int j2 = 0; j2 < 8; j2++) a[j2] += __shfl_xor(a[j2], 32);
#pragma unroll
        for (int off = 32; off; off >>= 1) wsum += __shfl_xor(wsum, off);
        const float inv = 1.0f / (wsum + 1e-16f);
        if (half == 0) {
            const float4 b0 = *(const float4*)(bias + f0);
            const float4 b1 = *(const float4*)(bias + f0 + 4);
            const float bb[8] = {b0.x, b0.y, b0.z, b0.w, b1.x, b1.y, b1.z, b1.w};
            us8 o;
#pragma unroll
            for (int j2 = 0; j2 < 8; j2++)
                o[j2] = f2us_rtn(fmaxf(a[j2] * inv + bb[j2], 0.f));
            *(us8*)(xout + (unsigned)((n << 8) + f0)) = o;
        }
    }
}

// ---- single-block (256 thr) scan over padded deg -> offs/cursor -------------
__device__ __forceinline__ void scan_body(const int* __restrict__ deg,
                                          int* __restrict__ offs,
                                          int* __restrict__ cursor,
                                          int N, int per, int* sums) {
    const int t = threadIdx.x;
    const int base = t * per;
    int s = 0;
    for (int i = 0; i < per; i += 4) {
        const int4 v = *(const int4*)(deg + base + i);
        s += v.x + v.y + v.z + v.w;
    }
    sums[t] = s;
    __syncthreads();
    for (int off = 1; off < 256; off <<= 1) {
        const int add = (t >= off) ? sums[t - off] : 0;
        __syncthreads();
        sums[t] += add;
        __syncthreads();
    }
    int run = (t > 0) ? sums[t - 1] : 0;
    for (int i = 0; i < per; i += 4) {
        const int4 v = *(const int4*)(deg + base + i);
        const int p = base + i;
        const int vv[4] = {v.x, v.y, v.z, v.w};
#pragma unroll
        for (int j = 0; j < 4; j++) {
            if (p + j < N) { offs[p + j] = run; cursor[p + j] = run; }
            run += vv[j];
        }
    }
    if (t == 255) offs[N] = run;   // pads are zero -> run == total
}

// =============================== mega kernel =================================
struct MegaArgs {
    const float *obs, *W1, *a1s, *a1d, *b1, *W2w, *a2s, *a2d, *b2, *Wm1, *bm1, *Wm2, *bm2;
    const int *srcA, *dstA;
    unsigned short *h, *xb, *obsb, *W1t, *W2t, *Wmt;
    float *as1, *ad1, *as2, *ad2, *y1;
    int *deg, *offs, *cursor, *esrc;
    float* out;
    int N, E, Etot, Dd, Hh, Aout, Npad, per, ntiles;
};

__global__ __launch_bounds__(256, 4) void mega(MegaArgs a) {
    cg::grid_group grid = cg::this_grid();
    __shared__ int sums[256];          // scan
    __shared__ float sW2[256 * 8];     // head2 Wm2 stage (8 KB)
    const int tid = threadIdx.x, bid = blockIdx.x;
    const int G = gridDim.x;
    const int gsz = G * 256;
    const int gtid = bid * 256 + tid;

    // ---- P0: W^T bf16 x3 + zero-init + obs fp32->bf16 ----
    {
        const int totW = 3 * a.Dd * a.Hh;
        const int z4 = 4 * a.N;
        const int nObs8 = a.N * a.Dd / 8;
        const int total = totW + z4 + a.Npad + nObs8;
        for (int i = gtid; i < total; i += gsz) {
            int idx = i;
            if (idx < totW) {
                const int tot = a.Dd * a.Hh;
                const float* W;
                unsigned short* T;
                if (idx < tot) { W = a.W1; T = a.W1t; }
                else if (idx < 2 * tot) { W = a.W2w; T = a.W2t; idx -= tot; }
                else { W = a.Wm1; T = a.Wmt; idx -= 2 * tot; }
                const int n = idx / a.Dd, k = idx - n * a.Dd;
                T[idx] = f2us_rtn(W[(size_t)k * a.Hh + n]);
                continue;
            }
            idx -= totW;
            if (idx < z4) {
                if (idx < a.N) a.as1[idx] = 0.f;
                else if (idx < 2 * a.N) a.ad1[idx - a.N] = 0.f;
                else if (idx < 3 * a.N) a.as2[idx - 2 * a.N] = 0.f;
                else a.ad2[idx - 3 * a.N] = 0.f;
                continue;
            }
            idx -= z4;
            if (idx < a.Npad) { a.deg[idx] = 0; continue; }
            idx -= a.Npad;
            {
                const float4 v0 = *(const float4*)(a.obs + (size_t)idx * 8);
                const float4 v1 = *(const float4*)(a.obs + (size_t)idx * 8 + 4);
                const float f[8] = {v0.x, v0.y, v0.z, v0.w, v1.x, v1.y, v1.z, v1.w};
                short8 o;
#pragma unroll
                for (int e = 0; e < 8; e++) o[e] = (short)f2us_rtn(f[e]);
                *(short8*)(a.obsb + (size_t)idx * 8) = o;
            }
        }
    }
    grid.sync();
    // ---- P1: count (blocks 0-63)  ||  gemm1 (blocks 64+) ----
    const int crew = G - 64;
    if (bid < 64) {
        for (int e = bid * 256 + tid; e < a.Etot; e += 64 * 256) {
            const int d = (e < a.E) ? a.dstA[e] : (e - a.E);
            atomicAdd(&a.deg[d], 1);
        }
    } else {
        for (int t = bid - 64; t < a.ntiles; t += crew)
            gemm_nolds<0>(a.obsb, a.W1t, a.a1s, a.a1d, a.as1, a.ad1, a.h, nullptr,
                          a.N, a.Hh, a.Dd, (t >> 1) * 64, (t & 1) * 128);
    }
    grid.sync();
    // ---- P2: scan (block 0) ----
    if (bid == 0) scan_body(a.deg, a.offs, a.cursor, a.N, a.per, sums);
    grid.sync();
    // ---- P3: scatter ----
    for (int e = gtid; e < a.Etot; e += gsz) {
        int s, d;
        if (e < a.E) { s = a.srcA[e]; d = a.dstA[e]; } else { s = d = e - a.E; }
        const int slot = atomicAdd(&a.cursor[d], 1);
        a.esrc[slot] = s;
    }
    grid.sync();
    // ---- P4: agg1 ----
    agg_phase(a.h, a.offs, a.esrc, a.as1, a.ad1, a.b1, a.xb, a.N, G * 4);
    grid.sync();
    // ---- P5: gemm2 ----
    for (int t = bid; t < a.ntiles; t += G)
        gemm_nolds<0>(a.xb, a.W2t, a.a2s, a.a2d, a.as2, a.ad2, a.h, nullptr,
                      a.N, a.Hh, a.Hh, (t >> 1) * 64, (t & 1) * 128);
    grid.sync();
    // ---- P6: agg2 ----
    agg_phase(a.h, a.offs, a.esrc, a.as2, a.ad2, a.b2, a.xb, a.N, G * 4);
    grid.sync();
    // ---- P7: head1  y1 = relu(xb @ Wm1 + bm1)  (fp32) ----
    for (int t = bid; t < a.ntiles; t += G)
        gemm_nolds<1>(a.xb, a.Wmt, a.bm1, nullptr, nullptr, nullptr, nullptr, a.y1,
                      a.N, a.Hh, a.Hh, (t >> 1) * 64, (t & 1) * 128);
    grid.sync();
    // ---- P8: head2  out = tanh(y1 @ Wm2 + bm2) ----
    for (int i = tid; i < a.Hh * 8; i += 256) sW2[i] = a.Wm2[i];
    __syncthreads();
    {
        float b2r[8];
#pragma unroll
        for (int q = 0; q < 8; q++) b2r[q] = a.bm2[q];
        for (int r = gtid; r < a.N; r += gsz) {
            const float* row = a.y1 + (size_t)r * a.Hh;
            float accv[8] = {};
            for (int d = 0; d < a.Hh; d += 4) {
                const float4 x4 = *(const float4*)(row + d);
                const float xs[4] = {x4.x, x4.y, x4.z, x4.w};
#pragma unroll
                for (int e = 0; e < 4; e++) {
                    const float x = xs[e];
                    const float4 w0 = *(const float4*)&sW2[(d + e) * 8];
                    const float4 w1 = *(const float4*)&sW2[(d + e) * 8 + 4];
                    accv[0] = fmaf(x, w0.x, accv[0]);
                    accv[1] = fmaf(x, w0.y, accv[1]);
                    accv[2] = fmaf(x, w0.z, accv[2]);
                    accv[3] = fmaf(x, w0.w, accv[3]);
                    accv[4] = fmaf(x, w1.x, accv[4]);
                    accv[5] = fmaf(x, w1.y, accv[5]);
                    accv[6] = fmaf(x, w1.z, accv[6]);
                    accv[7] = fmaf(x, w1.w, accv[7]);
                }
            }
#pragma unroll
            for (int q = 0; q < 8; q++)
                a.out[(size_t)r * 8 + q] = tanhf(accv[q] + b2r[q]);
        }
    }
}

// =========================== fallback kernels ================================
__global__ void prep_all(const float* __restrict__ Wa, const float* __restrict__ Wb,
                         const float* __restrict__ Wc, const float* __restrict__ obs,
                         unsigned short* __restrict__ TA, unsigned short* __restrict__ TB,
                         unsigned short* __restrict__ TC, unsigned short* __restrict__ obsb,
                         float* __restrict__ as1, float* __restrict__ ad1,
                         float* __restrict__ as2, float* __restrict__ ad2,
                         int* __restrict__ deg,
                         int K, int Nn, int N, int nObs8) {
    const int tot = K * Nn;
    int idx = blockIdx.x * blockDim.x + threadIdx.x;
    if (idx < 3 * tot) {
        const float* W;
        unsigned short* T;
        if (idx < tot) { W = Wa; T = TA; }
        else if (idx < 2 * tot) { W = Wb; T = TB; idx -= tot; }
        else { W = Wc; T = TC; idx -= 2 * tot; }
        const int n = idx / K, k = idx - n * K;
        T[idx] = f2us_rtn(W[(size_t)k * Nn + n]);
        return;
    }
    idx -= 3 * tot;
    if (idx < 5 * N) {
        if (idx < N) as1[idx] = 0.f;
        else if (idx < 2 * N) ad1[idx - N] = 0.f;
        else if (idx < 3 * N) as2[idx - 2 * N] = 0.f;
        else if (idx < 4 * N) ad2[idx - 3 * N] = 0.f;
        else deg[idx - 4 * N] = 0;
        return;
    }
    idx -= 5 * N;
    if (idx < nObs8) {
        const float4 a = *(const float4*)(obs + (size_t)idx * 8);
        const float4 b = *(const float4*)(obs + (size_t)idx * 8 + 4);
        const float f[8] = {a.x, a.y, a.z, a.w, b.x, b.y, b.z, b.w};
        short8 o;
#pragma unroll
        for (int e = 0; e < 8; e++) o[e] = (short)f2us_rtn(f[e]);
        *(short8*)(obsb + (size_t)idx * 8) = o;
    }
}

__global__ __launch_bounds__(256) void gemm_mfma_k(const unsigned short* __restrict__ A,
                                                   const unsigned short* __restrict__ Bt,
                                                   const float* __restrict__ avs,
                                                   const float* __restrict__ avd,
                                                   float* __restrict__ as_,
                                                   float* __restrict__ ad_,
                                                   unsigned short* __restrict__ C,
                                                   int M, int Nn, int K) {
    __shared__ unsigned short sA[64 * LP];
    __shared__ unsigned short sB[128 * LP];
    gemm_tile(A, Bt, avs, avd, as_, ad_, C, M, Nn, K,
              blockIdx.x * 64, blockIdx.y * 128, sA, sB);
}

__global__ __launch_bounds__(256) void gemm_head_k(const unsigned short* __restrict__ A,
                                                   const unsigned short* __restrict__ Bt,
                                                   const float* __restrict__ bias1,
                                                   const float* __restrict__ W2,
                                                   const float* __restrict__ bias2,
                                                   float* __restrict__ out,
                                                   int M, int K, int Aout) {
    __shared__ unsigned short sA[64 * LP];
    __shared__ unsigned short sB[256 * LP];
    __shared__ float pLDS[2 * 64 * 8];
    head_tile(A, Bt, bias1, W2, bias2, out, M, K, Aout, blockIdx.x * 64, sA, sB, pLDS);
}

__global__ void count_kernel(const int* __restrict__ dstA, int* __restrict__ deg, int E, int Etot) {
    const int e = blockIdx.x * blockDim.x + threadIdx.x;
    if (e >= Etot) return;
    const int d = (e < E) ? dstA[e] : (e - E);
    atomicAdd(&deg[d], 1);
}

__global__ __launch_bounds__(1024) void scan_kernel(const int* __restrict__ deg,
                                                    int* __restrict__ offs,
                                                    int* __restrict__ cursor, int N) {
    __shared__ int sums[1024];
    const int t = threadIdx.x;
    const int chunk = (N + 1023) / 1024;
    const int start = t * chunk;
    int s = 0;
    for (int i = 0; i < chunk; i++) {
        const int p = start + i;
        if (p < N) s += deg[p];
    }
    sums[t] = s;
    __syncthreads();
    for (int off = 1; off < 1024; off <<= 1) {
        const int add = (t >= off) ? sums[t - off] : 0;
        __syncthreads();
        sums[t] += add;
        __syncthreads();
    }
    int run = (t > 0) ? sums[t - 1] : 0;
    for (int i = 0; i < chunk; i++) {
        const int p = start + i;
        if (p < N) { offs[p] = run; cursor[p] = run; run += deg[p]; }
    }
    if (t == 0) offs[N] = sums[1023];
}

__global__ void scatter_kernel(const int* __restrict__ srcA, const int* __restrict__ dstA,
                               int* __restrict__ cursor, int* __restrict__ esrc, int E, int Etot) {
    const int e = blockIdx.x * blockDim.x + threadIdx.x;
    if (e >= Etot) return;
    int s, d;
    if (e < E) { s = srcA[e]; d = dstA[e]; } else { s = d = e - E; }
    const int slot = atomicAdd(&cursor[d], 1);
    esrc[slot] = s;
}

__global__ __launch_bounds__(256) void agg_kernel(const unsigned short* __restrict__ hb,
                                                  const int* __restrict__ offs,
                                                  const int* __restrict__ esrc,
                                                  const float* __restrict__ as_,
                                                  const float* __restrict__ ad_,
                                                  const float* __restrict__ bias,
                                                  unsigned short* __restrict__ xout, int N) {
    agg_phase(hb, offs, esrc, as_, ad_, bias, xout, N, gridDim.x * 4);
}

extern "C" void kernel_launch(void* const* d_in, const int* in_sizes, int n_in,
                              void* d_out, int out_size, void* d_ws, size_t ws_size,
                              hipStream_t stream) {
    const float* obs = (const float*)d_in[0];
    const int* eidx  = (const int*)d_in[1];
    const float* W1  = (const float*)d_in[2];
    const float* a1s = (const float*)d_in[3];
    const float* a1d = (const float*)d_in[4];
    const float* b1  = (const float*)d_in[5];
    const float* W2  = (const float*)d_in[6];
    const float* a2s = (const float*)d_in[7];
    const float* a2d = (const float*)d_in[8];
    const float* b2v = (const float*)d_in[9];
    const float* Wm1 = (const float*)d_in[10];
    const float* bm1 = (const float*)d_in[11];
    const float* Wm2 = (const float*)d_in[12];
    const float* bm2 = (const float*)d_in[13];
    float* out = (float*)d_out;

    const int Hh = in_sizes[3];            // 256
    const int Dd = in_sizes[2] / Hh;       // 256
    const int N  = in_sizes[0] / Dd;       // 20000
    const int E  = in_sizes[1] / 2;        // 320000
    const int Etot = E + N;                // 340000 (with self-loops)
    const int Aout = in_sizes[12] / Hh;    // 8

    const int* srcA = eidx;
    const int* dstA = eidx + E;

    const int per = ((N + 1023) / 1024) * 4;   // multiple of 4
    const int Npad = 256 * per;

    size_t off = 0;
    char* ws = (char*)d_ws;
    auto alloc = [&](size_t bytes) -> char* {
        char* p = ws + off;
        off = (off + bytes + 15) & ~(size_t)15;
        return p;
    };
    unsigned short* h    = (unsigned short*)alloc((size_t)N * Hh * 2);
    unsigned short* xb   = (unsigned short*)alloc((size_t)N * Hh * 2);
    unsigned short* obsb = (unsigned short*)alloc((size_t)N * Dd * 2);
    float* y1    = (float*)alloc((size_t)N * Hh * 4);
    float* as1   = (float*)alloc((size_t)N * 4);
    float* ad1   = (float*)alloc((size_t)N * 4);
    float* as2   = (float*)alloc((size_t)N * 4);
    float* ad2   = (float*)alloc((size_t)N * 4);
    int* deg     = (int*)alloc((size_t)Npad * 4);
    int* offs    = (int*)alloc((size_t)(N + 1) * 4);
    int* cursor  = (int*)alloc((size_t)N * 4);
    int* esrc    = (int*)alloc((size_t)Etot * 4);
    const size_t wsz = (size_t)Dd * Hh;    // 65536
    unsigned short* W1t = (unsigned short*)alloc(wsz * 2);
    unsigned short* W2t = (unsigned short*)alloc(wsz * 2);
    unsigned short* Wmt = (unsigned short*)alloc(wsz * 2);

    const int nrow = (N + 63) / 64;              // 313
    const int ntiles = nrow * (Hh / 128);        // 626

    // ---- try cooperative mega-kernel ----
    int nb = 0;
    hipError_t qe = hipOccupancyMaxActiveBlocksPerMultiprocessor(&nb, mega, 256, 0);
    int G = (qe == hipSuccess && nb > 0) ? nb * 256 : 0;
    if (G > 1024) G = 1024;
    if (G >= 256) {
        MegaArgs ma;
        ma.obs = obs; ma.W1 = W1; ma.a1s = a1s; ma.a1d = a1d; ma.b1 = b1;
        ma.W2w = W2; ma.a2s = a2s; ma.a2d = a2d; ma.b2 = b2v;
        ma.Wm1 = Wm1; ma.bm1 = bm1; ma.Wm2 = Wm2; ma.bm2 = bm2;
        ma.srcA = srcA; ma.dstA = dstA;
        ma.h = h; ma.xb = xb; ma.obsb = obsb; ma.W1t = W1t; ma.W2t = W2t; ma.Wmt = Wmt;
        ma.as1 = as1; ma.ad1 = ad1; ma.as2 = as2; ma.ad2 = ad2; ma.y1 = y1;
        ma.deg = deg; ma.offs = offs; ma.cursor = cursor; ma.esrc = esrc;
        ma.out = out;
        ma.N = N; ma.E = E; ma.Etot = Etot; ma.Dd = Dd; ma.Hh = Hh; ma.Aout = Aout;
        ma.Npad = Npad; ma.per = per; ma.ntiles = ntiles;
        void* kargs[] = { (void*)&ma };
        hipError_t le = hipLaunchCooperativeKernel(mega, dim3(G), dim3(256), kargs, 0, stream);
        if (le == hipSuccess) return;
    }

    // ---- fallback: proven 9-kernel path ----
    const int eb = 256;
    const int eg = (Etot + eb - 1) / eb;
    const dim3 ggrid(nrow, Hh / 128);
    const int nb4 = (N + 3) / 4;
    const int nObs8 = N * Dd / 8;

    const int ptot = 3 * (int)wsz + 5 * N + nObs8;
    prep_all<<<(ptot + 255) / 256, 256, 0, stream>>>(
        W1, W2, Wm1, obs, W1t, W2t, Wmt, obsb, as1, ad1, as2, ad2, deg, Dd, Hh, N, nObs8);
    count_kernel<<<eg, eb, 0, stream>>>(dstA, deg, E, Etot);
    scan_kernel<<<1, 1024, 0, stream>>>(deg, offs, cursor, N);
    scatter_kernel<<<eg, eb, 0, stream>>>(srcA, dstA, cursor, esrc, E, Etot);
    gemm_mfma_k<<<ggrid, 256, 0, stream>>>(obsb, W1t, a1s, a1d, as1, ad1, h, N, Hh, Dd);
    agg_kernel<<<nb4, 256, 0, stream>>>(h, offs, esrc, as1, ad1, b1, xb, N);
    gemm_mfma_k<<<ggrid, 256, 0, stream>>>(xb, W2t, a2s, a2d, as2, ad2, h, N, Hh, Hh);
    agg_kernel<<<nb4, 256, 0, stream>>>(h, offs, esrc, as2, ad2, b2v, xb, N);
    gemm_head_k<<<nrow, 256, 0, stream>>>(xb, Wmt, bm1, Wm2, bm2, out, N, Hh, Aout);
}

// Round 5
// 269.466 us; speedup vs baseline: 2.9695x; 2.9695x over previous
//
#include <hip/hip_runtime.h>
#include <hip/hip_bf16.h>
#include <math.h>

typedef __attribute__((ext_vector_type(8))) short short8;   // 8 bf16 (4 VGPRs)
typedef __attribute__((ext_vector_type(4))) float f32x4;
typedef __attribute__((ext_vector_type(8))) unsigned short us8;

__device__ __forceinline__ float us2f(unsigned short u) {
    return __uint_as_float(((unsigned)u) << 16);
}
__device__ __forceinline__ unsigned short f2us_rtn(float f) {
    return (unsigned short)__bfloat16_as_ushort(__float2bfloat16(f));  // RTN
}

// ---- prep: W^T bf16 x3 + zero-init (deg, as/ad x4) + obs fp32->bf16 --------
__global__ void prep_all(const float* __restrict__ Wa, const float* __restrict__ Wb,
                         const float* __restrict__ Wc, const float* __restrict__ obs,
                         unsigned short* __restrict__ TA, unsigned short* __restrict__ TB,
                         unsigned short* __restrict__ TC, unsigned short* __restrict__ obsb,
                         float* __restrict__ as1, float* __restrict__ ad1,
                         float* __restrict__ as2, float* __restrict__ ad2,
                         int* __restrict__ deg,
                         int K, int Nn, int N, int nObs8) {
    const int tot = K * Nn;
    int idx = blockIdx.x * blockDim.x + threadIdx.x;
    if (idx < 3 * tot) {
        const float* W;
        unsigned short* T;
        if (idx < tot) { W = Wa; T = TA; }
        else if (idx < 2 * tot) { W = Wb; T = TB; idx -= tot; }
        else { W = Wc; T = TC; idx -= 2 * tot; }
        const int n = idx / K, k = idx - n * K;
        T[idx] = f2us_rtn(W[(size_t)k * Nn + n]);
        return;
    }
    idx -= 3 * tot;
    if (idx < 5 * N) {
        if (idx < N) as1[idx] = 0.f;
        else if (idx < 2 * N) ad1[idx - N] = 0.f;
        else if (idx < 3 * N) as2[idx - 2 * N] = 0.f;
        else if (idx < 4 * N) ad2[idx - 3 * N] = 0.f;
        else deg[idx - 4 * N] = 0;
        return;
    }
    idx -= 5 * N;
    if (idx < nObs8) {
        const float4 a = *(const float4*)(obs + (size_t)idx * 8);
        const float4 b = *(const float4*)(obs + (size_t)idx * 8 + 4);
        const float f[8] = {a.x, a.y, a.z, a.w, b.x, b.y, b.z, b.w};
        short8 o;
#pragma unroll
        for (int e = 0; e < 8; e++) o[e] = (short)f2us_rtn(f[e]);
        *(short8*)(obsb + (size_t)idx * 8) = o;
    }
}

// ============ GAT GEMM: 64x64 tile, B panel staged ONCE, barrier-free K-loop =
// 4 waves; wave w owns rows [wr, wr+16). A fragments direct from global,
// prefetched 128-k ahead (4 short8 in flight). One __syncthreads total.
// Fragment k-index math identical to the verified layout (R1 numerics).
#define LPB 264   // 256 + 8 pad; row stride 528B = 33*16B (keeps b128 aligned)
__global__ __launch_bounds__(256, 4) void gemm_mfma(const unsigned short* __restrict__ A,
                                                    const unsigned short* __restrict__ Bt,
                                                    const float* __restrict__ avs,
                                                    const float* __restrict__ avd,
                                                    float* __restrict__ as_,
                                                    float* __restrict__ ad_,
                                                    unsigned short* __restrict__ C,
                                                    int M, int Nn, int K) {
    __shared__ unsigned short sB[64 * LPB];   // 33792 B
    const int tid = threadIdx.x;
    const int wave = tid >> 6, lane = tid & 63;
    const int m16 = lane & 15, quad = lane >> 4;
    const int row0 = blockIdx.x * 64, col0 = blockIdx.y * 64;
    const int wr = wave * 16;

    // stage B panel: thread t -> col c = t>>2, k-chunk (t&3)*64 (8x short8)
    {
        const int c = tid >> 2, kc0 = (tid & 3) * 64;
        const unsigned short* Bp = Bt + (size_t)(col0 + c) * K + kc0;
        unsigned short* dp = &sB[c * LPB + kc0];
#pragma unroll
        for (int j = 0; j < 8; j++)
            *(short8*)(dp + j * 8) = *(const short8*)(Bp + j * 8);
    }

    // A row pointer for this lane (row = m16, k-group = quad) [verified layout]
    int gr = row0 + wr + m16;
    if (gr >= M) gr = M - 1;
    const unsigned short* Arow = A + (size_t)gr * K + quad * 8;
    short8 a0 = *(const short8*)(Arow);
    short8 a1 = *(const short8*)(Arow + 32);
    short8 a2 = *(const short8*)(Arow + 64);
    short8 a3 = *(const short8*)(Arow + 96);
    __syncthreads();

    f32x4 acc[4] = {};
    const unsigned short* sBl = &sB[m16 * LPB + quad * 8];
#define BSTEP(af, kk)                                                              \
    {                                                                              \
        _Pragma("unroll")                                                          \
        for (int ni = 0; ni < 4; ni++) {                                           \
            const short8 bv = *(const short8*)(sBl + ni * (16 * LPB) + (kk));      \
            acc[ni] = __builtin_amdgcn_mfma_f32_16x16x32_bf16(af, bv, acc[ni], 0, 0, 0); \
        }                                                                          \
    }
    for (int k0 = 0; k0 < K; k0 += 128) {     // K % 128 == 0 here (K = 256)
        const bool more = (k0 + 128) < K;
        short8 n0, n1, n2, n3;
        if (more) {                            // next 4 A-frags in flight under MFMA
            n0 = *(const short8*)(Arow + k0 + 128);
            n1 = *(const short8*)(Arow + k0 + 160);
            n2 = *(const short8*)(Arow + k0 + 192);
            n3 = *(const short8*)(Arow + k0 + 224);
        }
        BSTEP(a0, k0)
        BSTEP(a1, k0 + 32)
        BSTEP(a2, k0 + 64)
        BSTEP(a3, k0 + 96)
        if (!more) break;
        a0 = n0; a1 = n1; a2 = n2; a3 = n3;
    }
#undef BSTEP

    // epilogue: C/D layout col=lane&15, row=quad*4+r [m89-verified]
    float ps[4] = {}, pd[4] = {};
    const int orow_base = row0 + wr + quad * 4;
#pragma unroll
    for (int ni = 0; ni < 4; ni++) {
        const int ocol = col0 + ni * 16 + m16;
        const float asv = avs[ocol], adv = avd[ocol];
#pragma unroll
        for (int r = 0; r < 4; r++) {
            const int orow = orow_base + r;
            if (orow < M) {
                const float v = acc[ni][r];
                C[(size_t)orow * Nn + ocol] = f2us_rtn(v);
                ps[r] = fmaf(v, asv, ps[r]);
                pd[r] = fmaf(v, adv, pd[r]);
            }
        }
    }
#pragma unroll
    for (int r = 0; r < 4; r++)
#pragma unroll
        for (int off = 1; off < 16; off <<= 1) {
            ps[r] += __shfl_xor(ps[r], off);
            pd[r] += __shfl_xor(pd[r], off);
        }
    if (m16 == 0) {
#pragma unroll
        for (int r = 0; r < 4; r++) {
            const int orow = orow_base + r;
            if (orow < M) {
                atomicAdd(&as_[orow], ps[r]);
                atomicAdd(&ad_[orow], pd[r]);
            }
        }
    }
}
#undef LPB

#define LP 72
// ---------------- MLP gemm + fused head (proven R1 body) ---------------------
__global__ __launch_bounds__(256) void gemm_head(const unsigned short* __restrict__ A,
                                                 const unsigned short* __restrict__ Bt,
                                                 const float* __restrict__ bias1,
                                                 const float* __restrict__ W2,
                                                 const float* __restrict__ bias2,
                                                 float* __restrict__ out,
                                                 int M, int K, int Aout) {
    __shared__ unsigned short sA[64 * LP];
    __shared__ unsigned short sB[256 * LP];
    __shared__ float pLDS[2][64][8];
    const int tid = threadIdx.x;
    const int wave = tid >> 6, lane = tid & 63;
    const int m16 = lane & 15, quad = lane >> 4;
    const int row0 = blockIdx.x * 64;
    const int wr = (wave >> 1) * 32, wc = (wave & 1) * 128;
    const int ar = tid >> 2, akc = (tid & 3) * 8;
    const int bkc = (tid & 7) * 8, bcb = tid >> 3;
    const int gr = (row0 + ar) < M ? (row0 + ar) : (M - 1);
    const unsigned short* Arow = A + (size_t)gr * K + akc;
    const unsigned short* Bcol = Bt + (size_t)bcb * K + bkc;

    short8 rA0, rA1, rb[8];
    auto LOADT = [&](int k0) {
        rA0 = *(const short8*)(Arow + k0);
        rA1 = *(const short8*)(Arow + k0 + 32);
#pragma unroll
        for (int q = 0; q < 8; q++)
            rb[q] = *(const short8*)(Bcol + (size_t)(32 * q) * K + k0);
    };
    auto STORET = [&]() {
        *(short8*)&sA[ar * LP + akc]      = rA0;
        *(short8*)&sA[ar * LP + akc + 32] = rA1;
#pragma unroll
        for (int q = 0; q < 8; q++)
            *(short8*)&sB[(bcb + 32 * q) * LP + bkc] = rb[q];
    };

    f32x4 acc[2][8] = {};
    LOADT(0);
    STORET();
    __syncthreads();
    for (int k0 = 0; k0 < K; k0 += 64) {
        const bool more = (k0 + 64) < K;
        if (more) LOADT(k0 + 64);
#pragma unroll
        for (int ks = 0; ks < 2; ks++) {
            short8 ah[2];
#pragma unroll
            for (int mi = 0; mi < 2; mi++)
                ah[mi] = *(const short8*)&sA[(wr + mi * 16 + m16) * LP + ks * 32 + quad * 8];
#pragma unroll
            for (int ni = 0; ni < 8; ni++) {
                const short8 bv = *(const short8*)&sB[(wc + ni * 16 + m16) * LP + ks * 32 + quad * 8];
#pragma unroll
                for (int mi = 0; mi < 2; mi++)
                    acc[mi][ni] = __builtin_amdgcn_mfma_f32_16x16x32_bf16(ah[mi], bv, acc[mi][ni], 0, 0, 0);
            }
        }
        __syncthreads();
        if (more) { STORET(); __syncthreads(); }
    }
    float p[2][4][8] = {};
#pragma unroll
    for (int ni = 0; ni < 8; ni++) {
        const int ocol = wc + ni * 16 + m16;
        const float b1v = bias1[ocol];
        float w2[8];
#pragma unroll
        for (int a = 0; a < 8; a++) w2[a] = W2[ocol * 8 + a];
#pragma unroll
        for (int mi = 0; mi < 2; mi++)
#pragma unroll
            for (int r = 0; r < 4; r++) {
                const float v = fmaxf(acc[mi][ni][r] + b1v, 0.f);
#pragma unroll
                for (int a = 0; a < 8; a++) p[mi][r][a] = fmaf(v, w2[a], p[mi][r][a]);
            }
    }
#pragma unroll
    for (int off = 1; off < 16; off <<= 1)
#pragma unroll
        for (int mi = 0; mi < 2; mi++)
#pragma unroll
            for (int r = 0; r < 4; r++)
#pragma unroll
                for (int a = 0; a < 8; a++) p[mi][r][a] += __shfl_xor(p[mi][r][a], off);
    if (m16 == 0) {
        const int half = wc >> 7;
#pragma unroll
        for (int mi = 0; mi < 2; mi++) {
            const int lrow = wr + mi * 16 + quad * 4;
#pragma unroll
            for (int r = 0; r < 4; r++)
#pragma unroll
                for (int a = 0; a < 8; a++) pLDS[half][lrow + r][a] = p[mi][r][a];
        }
    }
    __syncthreads();
#pragma unroll
    for (int u = 0; u < 2; u++) {
        const int idx = tid * 2 + u;
        const int lrow = idx >> 3, a = idx & 7;
        const int orow = row0 + lrow;
        if (orow < M && a < Aout)
            out[(size_t)orow * Aout + a] =
                tanhf(pLDS[0][lrow][a] + pLDS[1][lrow][a] + bias2[a]);
    }
}
#undef LP

// ---------------- CSR build ----------------
__global__ void count_kernel(const int* __restrict__ dstA, int* __restrict__ deg, int E, int Etot) {
    const int e = blockIdx.x * blockDim.x + threadIdx.x;
    if (e >= Etot) return;
    const int d = (e < E) ? dstA[e] : (e - E);
    atomicAdd(&deg[d], 1);
}

__global__ __launch_bounds__(1024) void scan_kernel(const int* __restrict__ deg,
                                                    int* __restrict__ offs,
                                                    int* __restrict__ cursor, int N) {
    __shared__ int sums[1024];
    const int t = threadIdx.x;
    const int chunk = (N + 1023) / 1024;
    const int start = t * chunk;
    int s = 0;
    for (int i = 0; i < chunk; i++) {
        const int p = start + i;
        if (p < N) s += deg[p];
    }
    sums[t] = s;
    __syncthreads();
    for (int off = 1; off < 1024; off <<= 1) {
        const int add = (t >= off) ? sums[t - off] : 0;
        __syncthreads();
        sums[t] += add;
        __syncthreads();
    }
    int run = (t > 0) ? sums[t - 1] : 0;
    for (int i = 0; i < chunk; i++) {
        const int p = start + i;
        if (p < N) { offs[p] = run; cursor[p] = run; run += deg[p]; }
    }
    if (t == 0) offs[N] = sums[1023];
}

__global__ void scatter_kernel(const int* __restrict__ srcA, const int* __restrict__ dstA,
                               int* __restrict__ cursor, int* __restrict__ esrc, int E, int Etot) {
    const int e = blockIdx.x * blockDim.x + threadIdx.x;
    if (e >= Etot) return;
    int s, d;
    if (e < E) { s = srcA[e]; d = dstA[e]; } else { s = d = e - E; }
    const int slot = atomicAdd(&cursor[d], 1);
    esrc[slot] = s;
}

// ---- fused softmax+aggregation (proven R1 body) -----------------------------
__global__ __launch_bounds__(256) void agg_kernel(const unsigned short* __restrict__ hb,
                                                  const int* __restrict__ offs,
                                                  const int* __restrict__ esrc,
                                                  const float* __restrict__ as_,
                                                  const float* __restrict__ ad_,
                                                  const float* __restrict__ bias,
                                                  unsigned short* __restrict__ xout, int N) {
    const int n = __builtin_amdgcn_readfirstlane(blockIdx.x * 4 + (threadIdx.x >> 6));
    if (n >= N) return;
    const int lane = threadIdx.x & 63;
    const int half = lane >> 5;
    const int f0 = (lane & 31) * 8;
    const int b = offs[n], e2 = offs[n + 1];
    const float adn = ad_[n];
    float a[8] = {};
    float wsum = 0.f;
    for (int c0 = b; c0 < e2; c0 += 16) {
        int s = 0;
        float w = 0.f;
        if (lane < 16) {
            const int j = c0 + lane;
            const int jj = j < e2 ? j : e2 - 1;     // self-loop guarantees >= 1 edge
            s = esrc[jj];
            if (j < e2) {
                float v = as_[s] + adn;
                v = v > 0.f ? v : 0.2f * v;
                w = __expf(v);
                wsum += w;
            }
        }
        us8 pv[8];
        float wb[8];
#pragma unroll
        for (int u = 0; u < 8; u++) {
            const int el = 2 * u + half;
            const int su = __shfl(s, el);
            wb[u] = __shfl(w, el);
            pv[u] = *(const us8*)(hb + (unsigned)((su << 8) + f0));
        }
#pragma unroll
        for (int u = 0; u < 8; u++)
#pragma unroll
            for (int j2 = 0; j2 < 8; j2++)
                a[j2] = fmaf(wb[u], us2f(pv[u][j2]), a[j2]);
    }
#pragma unroll
    for (int j2 = 0; j2 < 8; j2++) a[j2] += __shfl_xor(a[j2], 32);
#pragma unroll
    for (int off = 32; off; off >>= 1) wsum += __shfl_xor(wsum, off);
    const float inv = 1.0f / (wsum + 1e-16f);
    if (half == 0) {
        const float4 b0 = *(const float4*)(bias + f0);
        const float4 b1 = *(const float4*)(bias + f0 + 4);
        const float bb[8] = {b0.x, b0.y, b0.z, b0.w, b1.x, b1.y, b1.z, b1.w};
        us8 o;
#pragma unroll
        for (int j2 = 0; j2 < 8; j2++)
            o[j2] = f2us_rtn(fmaxf(a[j2] * inv + bb[j2], 0.f));
        *(us8*)(xout + (unsigned)((n << 8) + f0)) = o;
    }
}

extern "C" void kernel_launch(void* const* d_in, const int* in_sizes, int n_in,
                              void* d_out, int out_size, void* d_ws, size_t ws_size,
                              hipStream_t stream) {
    const float* obs = (const float*)d_in[0];
    const int* eidx  = (const int*)d_in[1];
    const float* W1  = (const float*)d_in[2];
    const float* a1s = (const float*)d_in[3];
    const float* a1d = (const float*)d_in[4];
    const float* b1  = (const float*)d_in[5];
    const float* W2  = (const float*)d_in[6];
    const float* a2s = (const float*)d_in[7];
    const float* a2d = (const float*)d_in[8];
    const float* b2v = (const float*)d_in[9];
    const float* Wm1 = (const float*)d_in[10];
    const float* bm1 = (const float*)d_in[11];
    const float* Wm2 = (const float*)d_in[12];
    const float* bm2 = (const float*)d_in[13];
    float* out = (float*)d_out;

    const int Hh = in_sizes[3];            // 256
    const int Dd = in_sizes[2] / Hh;       // 256
    const int N  = in_sizes[0] / Dd;       // 20000
    const int E  = in_sizes[1] / 2;        // 320000
    const int Etot = E + N;                // 340000 (with self-loops)
    const int Aout = in_sizes[12] / Hh;    // 8

    const int* srcA = eidx;
    const int* dstA = eidx + E;

    size_t off = 0;
    char* ws = (char*)d_ws;
    auto alloc = [&](size_t bytes) -> char* {
        char* p = ws + off;
        off = (off + bytes + 15) & ~(size_t)15;
        return p;
    };
    unsigned short* h    = (unsigned short*)alloc((size_t)N * Hh * 2);
    unsigned short* xb   = (unsigned short*)alloc((size_t)N * Hh * 2);
    unsigned short* obsb = (unsigned short*)alloc((size_t)N * Dd * 2);
    float* as1   = (float*)alloc((size_t)N * 4);
    float* ad1   = (float*)alloc((size_t)N * 4);
    float* as2   = (float*)alloc((size_t)N * 4);
    float* ad2   = (float*)alloc((size_t)N * 4);
    int* deg     = (int*)alloc((size_t)N * 4);
    int* offs    = (int*)alloc((size_t)(N + 1) * 4);
    int* cursor  = (int*)alloc((size_t)N * 4);
    int* esrc    = (int*)alloc((size_t)Etot * 4);
    const size_t wsz = (size_t)Dd * Hh;    // 65536
    unsigned short* W1t = (unsigned short*)alloc(wsz * 2);
    unsigned short* W2t = (unsigned short*)alloc(wsz * 2);
    unsigned short* Wmt = (unsigned short*)alloc(wsz * 2);

    const int eb = 256;
    const int eg = (Etot + eb - 1) / eb;
    const int nrow = (N + 63) / 64;              // 313
    const dim3 ggrid(nrow, Hh / 64);             // 313 x 4 (64-col B-resident tiles)
    const int nb4 = (N + 3) / 4;
    const int nObs8 = N * Dd / 8;                // 640000

    // ---- prep (W^T bf16, zero-init, obs->bf16) ----
    const int ptot = 3 * (int)wsz + 5 * N + nObs8;
    prep_all<<<(ptot + 255) / 256, 256, 0, stream>>>(
        W1, W2, Wm1, obs, W1t, W2t, Wmt, obsb, as1, ad1, as2, ad2, deg, Dd, Hh, N, nObs8);

    // ---- CSR build ----
    count_kernel<<<eg, eb, 0, stream>>>(dstA, deg, E, Etot);
    scan_kernel<<<1, 1024, 0, stream>>>(deg, offs, cursor, N);
    scatter_kernel<<<eg, eb, 0, stream>>>(srcA, dstA, cursor, esrc, E, Etot);

    // ---- GAT layer 1 ----
    gemm_mfma<<<ggrid, 256, 0, stream>>>(obsb, W1t, a1s, a1d, as1, ad1, h, N, Hh, Dd);
    agg_kernel<<<nb4, 256, 0, stream>>>(h, offs, esrc, as1, ad1, b1, xb, N);

    // ---- GAT layer 2 ----
    gemm_mfma<<<ggrid, 256, 0, stream>>>(xb, W2t, a2s, a2d, as2, ad2, h, N, Hh, Hh);
    agg_kernel<<<nb4, 256, 0, stream>>>(h, offs, esrc, as2, ad2, b2v, xb, N);

    // ---- MLP + head (fused) ----
    gemm_head<<<nrow, 256, 0, stream>>>(xb, Wmt, bm1, Wm2, bm2, out, N, Hh, Aout);
}